// Round 3
// baseline (41.858 us; speedup 1.0000x reference)
//
#include <hip/hip_runtime.h>
#include <hip/hip_cooperative_groups.h>

namespace cg = cooperative_groups;

// out[n,m] = dot(note[n],W) - dot(lab[m],W) + b   (exact factorization)
// Single cooperative dispatch:
//   phase 1: all 2560 row-dots, wave-per-row coalesced, -> ws
//   grid.sync()
//   phase 2: each block fills its 8x512 output tile from ws (c staged in LDS)

#define N_ROWS 2048
#define M_ROWS 512
#define FDIM   256
#define NBLK   256          // 1 block/CU -> co-residency guaranteed
#define RPB    (N_ROWS / NBLK)   // 8 note rows per block in phase 2

__global__ __launch_bounds__(256)
void siamese_coop(const float* __restrict__ note,
                  const float* __restrict__ lab,
                  const float* __restrict__ W,
                  const float* __restrict__ bptr,
                  float* __restrict__ out,
                  float* __restrict__ ws) {
    cg::grid_group grid = cg::this_grid();

    const int t    = threadIdx.x;    // 0..255
    const int blk  = blockIdx.x;     // 0..255
    const int wave = t >> 6;
    const int lane = t & 63;

    // ---- Phase 1: row dots (wave-per-row, full row = 64 lanes x float4) ----
    const float4 w4 = reinterpret_cast<const float4*>(W)[lane];
    const int gwave = blk * 4 + wave;             // 0..1023
    for (int r = gwave; r < N_ROWS + M_ROWS; r += NBLK * 4) {
        const float* row = (r < N_ROWS)
            ? note + (size_t)r * FDIM
            : lab  + (size_t)(r - N_ROWS) * FDIM;
        float4 v = reinterpret_cast<const float4*>(row)[lane];
        float s = v.x * w4.x + v.y * w4.y + v.z * w4.z + v.w * w4.w;
        #pragma unroll
        for (int off = 32; off > 0; off >>= 1)
            s += __shfl_down(s, off, 64);
        if (lane == 0) ws[r] = s;
    }

    grid.sync();

    // ---- Phase 2: fill rows [blk*8, blk*8+8) ----
    __shared__ float s_c[M_ROWS];   // all 512 lab dots
    __shared__ float s_a[RPB];      // this block's 8 note dots

    reinterpret_cast<float2*>(s_c)[t] =
        reinterpret_cast<const float2*>(ws + N_ROWS)[t];   // 256 x 8B = 512 floats
    if (t < RPB) s_a[t] = ws[blk * RPB + t];
    __syncthreads();

    const float bb = bptr[0];
    float4* out4 = reinterpret_cast<float4*>(out + (size_t)blk * RPB * M_ROWS);
    #pragma unroll
    for (int k = 0; k < 4; ++k) {
        const int idx = k * 256 + t;        // 0..1023
        const int r   = idx >> 7;           // 0..7
        const int mq  = idx & 127;          // float4 col
        const float  a = s_a[r] + bb;
        const float4 c = reinterpret_cast<const float4*>(s_c)[mq];
        float4 o;
        o.x = a - c.x;
        o.y = a - c.y;
        o.z = a - c.z;
        o.w = a - c.w;
        out4[idx] = o;
    }
}

extern "C" void kernel_launch(void* const* d_in, const int* in_sizes, int n_in,
                              void* d_out, int out_size, void* d_ws, size_t ws_size,
                              hipStream_t stream) {
    const float* note = (const float*)d_in[0];   // [N, F]
    const float* lab  = (const float*)d_in[1];   // [M, F]
    const float* W    = (const float*)d_in[2];   // [F]
    const float* b    = (const float*)d_in[3];   // [1]
    float* out        = (float*)d_out;           // [N, M]
    float* ws         = (float*)d_ws;            // >= (N+M) floats scratch

    void* args[] = { (void*)&note, (void*)&lab, (void*)&W, (void*)&b,
                     (void*)&out, (void*)&ws };
    hipLaunchCooperativeKernel((void*)siamese_coop,
                               dim3(NBLK), dim3(256), args, 0, stream);
}

// Round 4
// 19.039 us; speedup vs baseline: 2.1985x; 2.1985x over previous
//
#include <hip/hip_runtime.h>

// out[n,m] = dot(note[n],W) - dot(lab[m],W) + b   (exact factorization)
// ONE dispatch, no grid sync: 2D-tiled grid (32 x 8 = 256 blocks, 1/CU).
// Block (bn,bm) owns a 64x64 output tile; it computes the 64 note dots and
// 64 lab dots it needs itself, wave-per-row coalesced. Redundancy across
// blocks (~32 MB) is L2/L3-resident (note=2MB, lab=512KB).

#define N_ROWS 2048
#define M_ROWS 512
#define FDIM   256
#define GN     32
#define GM     8
#define TN     (N_ROWS / GN)   // 64 note rows / block
#define TM     (M_ROWS / GM)   // 64 lab rows / block

__global__ __launch_bounds__(256)
void siamese_tile(const float* __restrict__ note,
                  const float* __restrict__ lab,
                  const float* __restrict__ W,
                  const float* __restrict__ bptr,
                  float* __restrict__ out) {
    __shared__ float s_a[TN];   // note dots for this row band
    __shared__ float s_c[TM];   // lab dots for this col band

    const int t    = threadIdx.x;          // 0..255
    const int blk  = blockIdx.x;           // 0..255
    const int bn   = blk >> 3;             // 0..31
    const int bm   = blk & 7;              // 0..7
    const int wave = t >> 6;
    const int lane = t & 63;

    // W fragment per lane (row dot: lane i covers floats [4i,4i+4))
    const float4 w4 = reinterpret_cast<const float4*>(W)[lane];

    // ---- Dots: 128 rows (64 note + 64 lab), wave-per-row, stride 4 ----
    #pragma unroll 4
    for (int r = wave; r < TN + TM; r += 4) {
        const float* row = (r < TN)
            ? note + (size_t)(bn * TN + r) * FDIM
            : lab  + (size_t)(bm * TM + (r - TN)) * FDIM;
        float4 v = reinterpret_cast<const float4*>(row)[lane];
        float s = v.x * w4.x + v.y * w4.y + v.z * w4.z + v.w * w4.w;
        #pragma unroll
        for (int off = 32; off > 0; off >>= 1)
            s += __shfl_down(s, off, 64);
        if (lane == 0) {
            if (r < TN) s_a[r] = s;
            else        s_c[r - TN] = s;
        }
    }
    __syncthreads();

    // ---- Fill 64x64 tile: 1024 float4 stores, 4 per thread ----
    const float bb = bptr[0];
    float4* out4 = reinterpret_cast<float4*>(out);
    const int row_q = M_ROWS / 4;          // 128 float4 per full row
    #pragma unroll
    for (int k = 0; k < 4; ++k) {
        const int idx = k * 256 + t;       // 0..1023
        const int r   = idx >> 4;          // 0..63 tile row
        const int c4  = idx & 15;          // 0..15 tile float4 col
        const float  a = s_a[r] + bb;
        const float4 c = reinterpret_cast<const float4*>(s_c)[c4];
        float4 o;
        o.x = a - c.x;
        o.y = a - c.y;
        o.z = a - c.z;
        o.w = a - c.w;
        out4[(size_t)(bn * TN + r) * row_q + bm * (TM / 4) + c4] = o;
    }
}

extern "C" void kernel_launch(void* const* d_in, const int* in_sizes, int n_in,
                              void* d_out, int out_size, void* d_ws, size_t ws_size,
                              hipStream_t stream) {
    const float* note = (const float*)d_in[0];   // [N, F]
    const float* lab  = (const float*)d_in[1];   // [M, F]
    const float* W    = (const float*)d_in[2];   // [F]
    const float* b    = (const float*)d_in[3];   // [1]
    float* out        = (float*)d_out;           // [N, M]

    siamese_tile<<<GN * GM, 256, 0, stream>>>(note, lab, W, b, out);
}

// Round 5
// 12.016 us; speedup vs baseline: 3.4835x; 1.5845x over previous
//
#include <hip/hip_runtime.h>

// out[n,m] = dot(note[n],W) - dot(lab[m],W) + b   (exact factorization)
// ONE dispatch: 2D-tiled grid (32 x 8 = 256 blocks), 1024 threads (16 waves).
// Block (bn,bm) owns a 64x64 output tile; 128 row-dots (64 note + 64 lab)
// spread over 16 waves = 8 independent dots/wave (fully unrolled so the
// shuffle-reduce chains interleave -> throughput-bound, not latency-bound).

#define N_ROWS 2048
#define M_ROWS 512
#define FDIM   256
#define GN     32
#define GM     8
#define TN     (N_ROWS / GN)   // 64 note rows / block
#define TM     (M_ROWS / GM)   // 64 lab rows / block
#define WAVES  16

__global__ __launch_bounds__(1024)
void siamese_tile(const float* __restrict__ note,
                  const float* __restrict__ lab,
                  const float* __restrict__ W,
                  const float* __restrict__ bptr,
                  float* __restrict__ out) {
    __shared__ float s_a[TN];   // note dots for this row band
    __shared__ float s_c[TM];   // lab dots for this col band

    const int t    = threadIdx.x;          // 0..1023
    const int blk  = blockIdx.x;           // 0..255
    const int bn   = blk >> 3;             // 0..31
    const int bm   = blk & 7;              // 0..7
    const int wave = t >> 6;               // 0..15
    const int lane = t & 63;

    // W fragment per lane (row dot: lane i covers floats [4i,4i+4))
    const float4 w4 = reinterpret_cast<const float4*>(W)[lane];

    // ---- Dots: 128 rows (64 note + 64 lab); wave w takes r = w + 16*i ----
    #pragma unroll
    for (int i = 0; i < (TN + TM) / WAVES; ++i) {
        const int r = wave + i * WAVES;    // 0..127, wave-uniform branch below
        const float* row = (r < TN)
            ? note + (size_t)(bn * TN + r) * FDIM
            : lab  + (size_t)(bm * TM + (r - TN)) * FDIM;
        float4 v = reinterpret_cast<const float4*>(row)[lane];
        float s = v.x * w4.x + v.y * w4.y + v.z * w4.z + v.w * w4.w;
        #pragma unroll
        for (int off = 32; off > 0; off >>= 1)
            s += __shfl_down(s, off, 64);
        if (lane == 0) {
            if (r < TN) s_a[r] = s;
            else        s_c[r - TN] = s;
        }
    }
    __syncthreads();

    // ---- Fill 64x64 tile: 1024 float4 stores, one per thread ----
    const float bb = bptr[0];
    float4* out4 = reinterpret_cast<float4*>(out);
    const int row_q = M_ROWS / 4;          // 128 float4 per full output row
    const int r  = t >> 4;                 // 0..63 tile row
    const int c4 = t & 15;                 // 0..15 tile float4 col
    const float  a = s_a[r] + bb;
    const float4 c = reinterpret_cast<const float4*>(s_c)[c4];
    float4 o;
    o.x = a - c.x;
    o.y = a - c.y;
    o.z = a - c.z;
    o.w = a - c.w;
    out4[(size_t)(bn * TN + r) * row_q + bm * (TM / 4) + c4] = o;
}

extern "C" void kernel_launch(void* const* d_in, const int* in_sizes, int n_in,
                              void* d_out, int out_size, void* d_ws, size_t ws_size,
                              hipStream_t stream) {
    const float* note = (const float*)d_in[0];   // [N, F]
    const float* lab  = (const float*)d_in[1];   // [M, F]
    const float* W    = (const float*)d_in[2];   // [F]
    const float* b    = (const float*)d_in[3];   // [1]
    float* out        = (float*)d_out;           // [N, M]

    siamese_tile<<<GN * GM, 1024, 0, stream>>>(note, lab, W, b, out);
}

// Round 6
// 11.578 us; speedup vs baseline: 3.6152x; 1.0378x over previous
//
#include <hip/hip_runtime.h>

// out[n,m] = dot(note[n],W) - dot(lab[m],W) + b   (exact factorization)
// Best-measured structure (R1, 11.6us): two small dispatches.
//   k1: one 64-lane wave per row (2560 waves), shuffle-reduce -> ws.
//       note dots get +b folded in, so k2 is pure a[n] - c[m].
//   k2: float4-vectorized broadcast fill of the 2048x512 output.
// dur_us is dominated by ~10us fixed replay/launch overhead; kernel work
// floor is ~1us (2.5MB fetch + 4MB write at ~6.9 TB/s achieved).

#define N_ROWS 2048
#define M_ROWS 512
#define FDIM   256

__global__ __launch_bounds__(256)
void siamese_dots(const float* __restrict__ note,
                  const float* __restrict__ lab,
                  const float* __restrict__ W,
                  const float* __restrict__ bptr,
                  float* __restrict__ ws) {
    int gid  = blockIdx.x * blockDim.x + threadIdx.x;
    int wave = gid >> 6;          // global wave index, 0..2559
    int lane = threadIdx.x & 63;
    const int total = N_ROWS + M_ROWS;
    if (wave >= total) return;

    const float* row = (wave < N_ROWS)
        ? note + (size_t)wave * FDIM
        : lab  + (size_t)(wave - N_ROWS) * FDIM;

    float4 v = reinterpret_cast<const float4*>(row)[lane];
    float4 w = reinterpret_cast<const float4*>(W)[lane];
    float s = v.x * w.x + v.y * w.y + v.z * w.z + v.w * w.w;

    // 64-lane butterfly reduce
    #pragma unroll
    for (int off = 32; off > 0; off >>= 1)
        s += __shfl_down(s, off, 64);

    if (lane == 0) {
        // fold +b into the note dots so the fill kernel is a pure subtract
        ws[wave] = (wave < N_ROWS) ? s + bptr[0] : s;
    }
}

// k2: out[n,m] = a[n] - c[m]; one float4 per thread (262144 threads).
__global__ __launch_bounds__(256)
void siamese_fill(const float* __restrict__ ws,
                  float* __restrict__ out) {
    int idx = blockIdx.x * blockDim.x + threadIdx.x;   // float4 index
    int mq  = idx & (M_ROWS / 4 - 1);                  // 0..127
    int n   = idx >> 7;                                // 0..2047

    float a  = ws[n];                                  // includes +b
    float4 c = reinterpret_cast<const float4*>(ws + N_ROWS)[mq];

    float4 o;
    o.x = a - c.x;
    o.y = a - c.y;
    o.z = a - c.z;
    o.w = a - c.w;
    reinterpret_cast<float4*>(out)[idx] = o;
}

extern "C" void kernel_launch(void* const* d_in, const int* in_sizes, int n_in,
                              void* d_out, int out_size, void* d_ws, size_t ws_size,
                              hipStream_t stream) {
    const float* note = (const float*)d_in[0];   // [N, F]
    const float* lab  = (const float*)d_in[1];   // [M, F]
    const float* W    = (const float*)d_in[2];   // [F]
    const float* b    = (const float*)d_in[3];   // [1]
    float* out        = (float*)d_out;           // [N, M]
    float* ws         = (float*)d_ws;            // N + M floats of scratch

    {
        const int total_waves = N_ROWS + M_ROWS;          // 2560
        const int block = 256;
        const int waves_per_block = block / 64;           // 4
        const int grid = (total_waves + waves_per_block - 1) / waves_per_block; // 640
        siamese_dots<<<grid, block, 0, stream>>>(note, lab, W, b, ws);
    }
    {
        const int total = N_ROWS * (M_ROWS / 4);          // 262144 float4
        const int block = 256;
        const int grid = total / block;                   // 1024
        siamese_fill<<<grid, block, 0, stream>>>(ws, out);
    }
}